// Round 4
// baseline (480.380 us; speedup 1.0000x reference)
//
#include <hip/hip_runtime.h>
#include <math.h>

typedef __attribute__((ext_vector_type(4))) float f32x4;
typedef __attribute__((ext_vector_type(8))) __bf16 bf16x8;
typedef __attribute__((ext_vector_type(2))) __bf16 bf16x2;

#ifndef __has_builtin
#define __has_builtin(x) 0
#endif

#if __has_builtin(__builtin_amdgcn_exp2f)
#define EXP2F(x) __builtin_amdgcn_exp2f(x)
#else
#define EXP2F(x) exp2f(x)
#endif

__device__ __forceinline__ ushort f2bf(float f) {
  return (ushort)((__float_as_uint(f) + 0x8000u) >> 16);  // round-half-up
}

__device__ __forceinline__ uint pack_bf16(float a, float b) {
#if __has_builtin(__builtin_amdgcn_cvt_pk_bf16_f32)
  bf16x2 p = __builtin_amdgcn_cvt_pk_bf16_f32(a, b);
  return __builtin_bit_cast(uint, p);
#elif __has_builtin(__builtin_amdgcn_perm)
  uint au = __float_as_uint(a) + 0x8000u;
  uint bu = __float_as_uint(b) + 0x8000u;
  return __builtin_amdgcn_perm(bu, au, 0x07060302u);
#else
  return (uint)f2bf(a) | ((uint)f2bf(b) << 16);
#endif
}

// async global->LDS, 16B per lane; LDS dst is wave-uniform base (HW adds lane*16)
__device__ __forceinline__ void async_cp16(const void* g, void* l) {
  __builtin_amdgcn_global_load_lds(
      (const __attribute__((address_space(1))) void*)g,
      (__attribute__((address_space(3))) void*)l, 16, 0, 0);
}

// ---------------- small prep kernels ----------------

__global__ __launch_bounds__(256) void bias_kernel(const int* __restrict__ mask,
                                                   float* __restrict__ bias) {
  int i = blockIdx.x * 256 + threadIdx.x;  // 8192 total
  bias[i] = mask[i] ? 0.0f : -1e9f;
}

__global__ __launch_bounds__(256) void cast4_kernel(const float* __restrict__ a,
                                                    const float* __restrict__ b,
                                                    const float* __restrict__ c,
                                                    const float* __restrict__ d,
                                                    ushort* ao, ushort* bo, ushort* co, ushort* do_) {
  int y = blockIdx.y;
  const float* in = y == 0 ? a : (y == 1 ? b : (y == 2 ? c : d));
  ushort* out = y == 0 ? ao : (y == 1 ? bo : (y == 2 ? co : do_));
  int i = blockIdx.x * 256 + threadIdx.x;
  float4 f = ((const float4*)in)[i];
  uint2 o;
  o.x = pack_bf16(f.x, f.y);
  o.y = pack_bf16(f.z, f.w);
  ((uint2*)out)[i] = o;
}

// ---------------- GEMM: C[m,n] = sum_k A[m,k]*W[n,k], N=K=1024 ----------------
// mode 0: bf16 out row-major; mode 1: fp32 out row-major;
// mode 2: bf16 out per-head transposed: out[((b*16+h)*64+d)*2048 + s]
// mode 3: bf16 out row-major scaled by 0.125*log2(e)  (Q projection)
// AFP32: A is fp32, cast fused into LDS staging (ds_write path); else bf16 via global_load_lds.

template <bool AFP32>
__device__ __forceinline__ void gemm_body(const void* __restrict__ Ain,
                                          const ushort* __restrict__ W,
                                          void* __restrict__ Cout, int mode,
                                          int bm, int bn) {
  constexpr int N = 1024, K = 1024;
  __shared__ ushort As[128 * 32];  // chunk-blocked: elem(row,k) at ((k>>3)*128+row)*8+(k&7)
  __shared__ ushort Bs[128 * 32];
  const int tid = threadIdx.x;
  const int w = tid >> 6, lane = tid & 63;
  const int g = lane >> 4, cc = lane & 15;
  const int wm = (w >> 1) * 64, wn = (w & 1) * 64;

  f32x4 acc[4][4];
#pragma unroll
  for (int i = 0; i < 4; ++i)
#pragma unroll
    for (int j = 0; j < 4; ++j) acc[i][j] = (f32x4)0.0f;

  // fp32-A staging map: thread t owns chunks t (row=t&127, kb=t>>7) and t+256 (kb+2)
  const int arow = tid & 127, akb = tid >> 7;
  const float* aptr = AFP32 ? (const float*)Ain + (size_t)(bm + arow) * K + akb * 8 : nullptr;
  const ushort* Ab = (const ushort*)Ain;

  for (int k0 = 0; k0 < K; k0 += 32) {
    // B tile: async global->LDS (in flight across A staging)
#pragma unroll
    for (int jj = 0; jj < 2; ++jj) {
      int cbase = w * 128 + jj * 64;
      int cid = cbase + lane;
      int row = cid & 127, kb = cid >> 7;
      async_cp16(W + (size_t)(bn + row) * K + k0 + kb * 8, &Bs[cbase * 8]);
    }
    if (AFP32) {
      float4 a0 = *(const float4*)(aptr + k0);
      float4 a1 = *(const float4*)(aptr + k0 + 4);
      float4 a2 = *(const float4*)(aptr + k0 + 16);
      float4 a3 = *(const float4*)(aptr + k0 + 20);
      uint4 c0, c1;
      c0.x = pack_bf16(a0.x, a0.y); c0.y = pack_bf16(a0.z, a0.w);
      c0.z = pack_bf16(a1.x, a1.y); c0.w = pack_bf16(a1.z, a1.w);
      c1.x = pack_bf16(a2.x, a2.y); c1.y = pack_bf16(a2.z, a2.w);
      c1.z = pack_bf16(a3.x, a3.y); c1.w = pack_bf16(a3.z, a3.w);
      *(uint4*)&As[(size_t)tid * 8] = c0;
      *(uint4*)&As[(size_t)(tid + 256) * 8] = c1;
    } else {
#pragma unroll
      for (int jj = 0; jj < 2; ++jj) {
        int cbase = w * 128 + jj * 64;
        int cid = cbase + lane;
        int row = cid & 127, kb = cid >> 7;
        async_cp16(Ab + (size_t)(bm + row) * K + k0 + kb * 8, &As[cbase * 8]);
      }
    }
    __syncthreads();
    bf16x8 af[4], bfr[4];
#pragma unroll
    for (int mi = 0; mi < 4; ++mi)
      af[mi] = *(const bf16x8*)&As[(g * 128 + wm + mi * 16 + cc) * 8];
#pragma unroll
    for (int ni = 0; ni < 4; ++ni)
      bfr[ni] = *(const bf16x8*)&Bs[(g * 128 + wn + ni * 16 + cc) * 8];
#pragma unroll
    for (int mi = 0; mi < 4; ++mi)
#pragma unroll
      for (int ni = 0; ni < 4; ++ni)
        acc[mi][ni] = __builtin_amdgcn_mfma_f32_16x16x32_bf16(af[mi], bfr[ni], acc[mi][ni], 0, 0, 0);
    __syncthreads();
  }

  const float qsc = 0.18033688011112042f;
#pragma unroll
  for (int mi = 0; mi < 4; ++mi) {
#pragma unroll
    for (int ni = 0; ni < 4; ++ni) {
#pragma unroll
      for (int r = 0; r < 4; ++r) {
        int row = bm + wm + mi * 16 + g * 4 + r;
        int col = bn + wn + ni * 16 + cc;
        float val = acc[mi][ni][r];
        if (mode == 0) {
          ((ushort*)Cout)[(size_t)row * N + col] = f2bf(val);
        } else if (mode == 1) {
          ((float*)Cout)[(size_t)row * N + col] = val;
        } else if (mode == 3) {
          ((ushort*)Cout)[(size_t)row * N + col] = f2bf(val * qsc);
        } else {
          int b = row >> 11, s = row & 2047;
          int h = col >> 6, d = col & 63;
          ((ushort*)Cout)[(size_t)((b * 16 + h) * 64 + d) * 2048 + s] = f2bf(val);
        }
      }
    }
  }
}

// grid (8,64,3). XCD swizzle: xcd j owns y in [8j,8j+8) for all x,z -> per-XCD
// working set = A-stripes 2MB + W 2MB = one L2; A-stripe fetched by exactly one XCD.
__global__ __launch_bounds__(256) void qkv_gemm_kernel(const float* q, const float* k,
                                                       const float* v, const ushort* wq,
                                                       const ushort* wk, const ushort* wv,
                                                       ushort* Qp, ushort* Kp, ushort* Vt) {
  int lid = blockIdx.x + (blockIdx.y << 3) + (blockIdx.z << 9);
  int j = lid & 7, s = lid >> 3;
  int x = s & 7, yl = (s >> 3) & 7, z = s >> 6;
  int y = (j << 3) | yl;
  const float* A = z == 0 ? q : (z == 1 ? k : v);
  const ushort* W = z == 0 ? wq : (z == 1 ? wk : wv);
  void* C = z == 0 ? (void*)Qp : (z == 1 ? (void*)Kp : (void*)Vt);
  gemm_body<true>(A, W, C, z == 2 ? 2 : (z == 0 ? 3 : 0), y * 128, x * 128);
}

// grid (8,64), bf16 A (mh), fp32 out
__global__ __launch_bounds__(256) void gemm_wo_kernel(const ushort* A, const ushort* W,
                                                      float* C) {
  int lid = blockIdx.x + (blockIdx.y << 3);
  int j = lid & 7, s = lid >> 3;
  int x = s & 7, yl = s >> 3;
  int y = (j << 3) | yl;
  gemm_body<false>(A, W, C, 1, y * 128, x * 128);
}

// ---------------- flash attention (S^T form, exp2 domain) ----------------
// Qp: [B*S,1024] bf16 PRE-SCALED by 0.125*log2e. Kp: [B*S,1024] bf16.
// Vt: [B*H,64,2048] bf16. bias: [B,2048] fp32 (0 or -1e9). mh: [B*S,1024] bf16.
__global__ __launch_bounds__(256, 4) void attn_kernel(const ushort* __restrict__ Qp,
                                                      const ushort* __restrict__ Kp,
                                                      const ushort* __restrict__ Vt,
                                                      const float* __restrict__ bias,
                                                      ushort* __restrict__ mh) {
  constexpr int S = 2048, DM = 1024, DK = 64;
  __shared__ ushort k_lds[64 * 64];
  __shared__ ushort v_lds[64 * 64];
  __shared__ ushort pt_lds[4 * 2176];

  const int bh = blockIdx.x;
  const int qt = blockIdx.y;
  const int b = bh >> 4, h = bh & 15;
  const int tid = threadIdx.x;
  const int w = tid >> 6, lane = tid & 63;
  const int g = lane >> 4, cc = lane & 15;
  ushort* ptw = &pt_lds[w * 2176];

  const int q0 = qt * 128 + w * 32;
  bf16x8 qf[2][2];
#pragma unroll
  for (int ni = 0; ni < 2; ++ni) {
    size_t row = (size_t)(b * S + q0 + ni * 16 + cc);
#pragma unroll
    for (int ks = 0; ks < 2; ++ks)
      qf[ks][ni] = *(const bf16x8*)&Qp[row * DM + h * DK + ks * 32 + g * 8];
  }

  bf16x8 ones;
#pragma unroll
  for (int i = 0; i < 8; ++i) ones[i] = (__bf16)1.0f;

  f32x4 o_acc[4][2];
#pragma unroll
  for (int i = 0; i < 4; ++i)
#pragma unroll
    for (int j = 0; j < 2; ++j) o_acc[i][j] = (f32x4)0.0f;
  f32x4 l_acc[2] = {(f32x4)0.0f, (f32x4)0.0f};
  float m_i[2] = {-3e38f, -3e38f};
  const float* biasb = bias + b * S;

  for (int kt = 0; kt < S / 64; ++kt) {
    if (kt) __syncthreads();
#pragma unroll
    for (int j = 0; j < 2; ++j) {
      int cb = j * 256 + w * 64;
      int cid = cb + lane;
      async_cp16(Kp + (size_t)(b * S + kt * 64 + (cid & 63)) * DM + h * DK + (cid >> 6) * 8,
                 &k_lds[cb * 8]);
      async_cp16(Vt + (size_t)(bh * DK + (cid & 63)) * S + kt * 64 + (cid >> 6) * 8,
                 &v_lds[cb * 8]);
    }
    __syncthreads();

    f32x4 sacc[4][2];
#pragma unroll
    for (int mi = 0; mi < 4; ++mi)
#pragma unroll
      for (int ni = 0; ni < 2; ++ni) sacc[mi][ni] = (f32x4)0.0f;
#pragma unroll
    for (int ks = 0; ks < 2; ++ks)
#pragma unroll
      for (int mi = 0; mi < 4; ++mi) {
        bf16x8 kf = *(const bf16x8*)&k_lds[((ks * 4 + g) * 64 + mi * 16 + cc) * 8];
        sacc[mi][0] = __builtin_amdgcn_mfma_f32_16x16x32_bf16(kf, qf[ks][0], sacc[mi][0], 0, 0, 0);
        sacc[mi][1] = __builtin_amdgcn_mfma_f32_16x16x32_bf16(kf, qf[ks][1], sacc[mi][1], 0, 0, 0);
      }

    float mx[2] = {-3e38f, -3e38f};
#pragma unroll
    for (int mi = 0; mi < 4; ++mi) {
      float4 bv = *(const float4*)&biasb[kt * 64 + mi * 16 + g * 4];
      const float* bvp = &bv.x;
#pragma unroll
      for (int r = 0; r < 4; ++r) {
#pragma unroll
        for (int ni = 0; ni < 2; ++ni) {
          float t = sacc[mi][ni][r] + bvp[r];
          sacc[mi][ni][r] = t;
          mx[ni] = fmaxf(mx[ni], t);
        }
      }
    }
    float mn[2];
#pragma unroll
    for (int ni = 0; ni < 2; ++ni) {
      float m = mx[ni];
      m = fmaxf(m, __shfl_xor(m, 16, 64));
      m = fmaxf(m, __shfl_xor(m, 32, 64));
      mn[ni] = fmaxf(m_i[ni], m);
      float al = EXP2F(m_i[ni] - mn[ni]);
      m_i[ni] = mn[ni];
      l_acc[ni][0] *= al;
#pragma unroll
      for (int md = 0; md < 4; ++md)
#pragma unroll
        for (int r = 0; r < 4; ++r) o_acc[md][ni][r] *= al;
    }

#pragma unroll
    for (int mi = 0; mi < 4; ++mi)
#pragma unroll
      for (int ni = 0; ni < 2; ++ni) {
        float p0 = EXP2F(sacc[mi][ni][0] - mn[ni]);
        float p1 = EXP2F(sacc[mi][ni][1] - mn[ni]);
        float p2 = EXP2F(sacc[mi][ni][2] - mn[ni]);
        float p3 = EXP2F(sacc[mi][ni][3] - mn[ni]);
        uint2 pv;
        pv.x = pack_bf16(p0, p1);
        pv.y = pack_bf16(p2, p3);
        int base = ((mi * 2 + (g >> 1)) * 32 + ni * 16 + cc) * 8 + (g & 1) * 4;
        *(uint2*)&ptw[base] = pv;
      }

#pragma unroll
    for (int ks = 0; ks < 2; ++ks) {
      bf16x8 ptf[2];
#pragma unroll
      for (int ni = 0; ni < 2; ++ni)
        ptf[ni] = *(const bf16x8*)&ptw[((ks * 4 + g) * 32 + ni * 16 + cc) * 8];
      l_acc[0] = __builtin_amdgcn_mfma_f32_16x16x32_bf16(ones, ptf[0], l_acc[0], 0, 0, 0);
      l_acc[1] = __builtin_amdgcn_mfma_f32_16x16x32_bf16(ones, ptf[1], l_acc[1], 0, 0, 0);
#pragma unroll
      for (int md = 0; md < 4; ++md) {
        bf16x8 vf = *(const bf16x8*)&v_lds[((ks * 4 + g) * 64 + md * 16 + cc) * 8];
        o_acc[md][0] = __builtin_amdgcn_mfma_f32_16x16x32_bf16(vf, ptf[0], o_acc[md][0], 0, 0, 0);
        o_acc[md][1] = __builtin_amdgcn_mfma_f32_16x16x32_bf16(vf, ptf[1], o_acc[md][1], 0, 0, 0);
      }
    }
  }

  float rl[2];
#pragma unroll
  for (int ni = 0; ni < 2; ++ni) rl[ni] = 1.0f / l_acc[ni][0];

#pragma unroll
  for (int md = 0; md < 4; ++md)
#pragma unroll
    for (int ni = 0; ni < 2; ++ni) {
      int ql = ni * 16 + cc;
      int dbase = md * 16 + g * 4;
      *(uint*)&ptw[ql * 68 + dbase] =
          pack_bf16(o_acc[md][ni][0] * rl[ni], o_acc[md][ni][1] * rl[ni]);
      *(uint*)&ptw[ql * 68 + dbase + 2] =
          pack_bf16(o_acc[md][ni][2] * rl[ni], o_acc[md][ni][3] * rl[ni]);
    }
#pragma unroll
  for (int pass = 0; pass < 4; ++pass) {
    int ql = pass * 8 + (lane >> 3);
    int dc = lane & 7;
    uint4 val = *(const uint4*)&ptw[ql * 68 + dc * 8];
    *(uint4*)&mh[(size_t)(b * S + q0 + ql) * DM + h * DK + dc * 8] = val;
  }
}

// ---------------- launch ----------------
// ws (<=73 MB, proven): 0-16 Qp | 16-32 Kp | 32-48 Vt | 48-56 weights | 56 bias | 57-73 mh

extern "C" void kernel_launch(void* const* d_in, const int* in_sizes, int n_in,
                              void* d_out, int out_size, void* d_ws, size_t ws_size,
                              hipStream_t stream) {
  const float* q = (const float*)d_in[0];
  const float* k = (const float*)d_in[1];
  const float* v = (const float*)d_in[2];
  const int* mask = (const int*)d_in[3];
  const float* Wq = (const float*)d_in[4];
  const float* Wk = (const float*)d_in[5];
  const float* Wv = (const float*)d_in[6];
  const float* Wo = (const float*)d_in[7];

  const int Dm = 1024;
  const size_t MB = 1 << 20;

  char* ws = (char*)d_ws;
  ushort* Qp = (ushort*)(ws);
  ushort* Kp = (ushort*)(ws + 16 * MB);
  ushort* Vt = (ushort*)(ws + 32 * MB);
  ushort* wqb = (ushort*)(ws + 48 * MB);
  ushort* wkb = wqb + (1 << 20);
  ushort* wvb = wkb + (1 << 20);
  ushort* wob = wvb + (1 << 20);
  float* biasbuf = (float*)(ws + 56 * MB);
  ushort* mh = (ushort*)(ws + 57 * MB);

  dim3 blk(256);

  cast4_kernel<<<dim3(1024, 4), blk, 0, stream>>>(Wq, Wk, Wv, Wo, wqb, wkb, wvb, wob);
  bias_kernel<<<dim3(32), blk, 0, stream>>>(mask, biasbuf);
  qkv_gemm_kernel<<<dim3(8, 64, 3), blk, 0, stream>>>(q, k, v, wqb, wkb, wvb, Qp, Kp, Vt);
  attn_kernel<<<dim3(64, 16), blk, 0, stream>>>(Qp, Kp, Vt, biasbuf, mh);
  gemm_wo_kernel<<<dim3(8, 64), blk, 0, stream>>>(mh, wob, (float*)d_out);
}

// Round 5
// 436.090 us; speedup vs baseline: 1.1016x; 1.1016x over previous
//
#include <hip/hip_runtime.h>
#include <math.h>

typedef __attribute__((ext_vector_type(4))) float f32x4;
typedef __attribute__((ext_vector_type(8))) __bf16 bf16x8;
typedef __attribute__((ext_vector_type(2))) __bf16 bf16x2;

#ifndef __has_builtin
#define __has_builtin(x) 0
#endif

#if __has_builtin(__builtin_amdgcn_exp2f)
#define EXP2F(x) __builtin_amdgcn_exp2f(x)
#else
#define EXP2F(x) exp2f(x)
#endif

__device__ __forceinline__ ushort f2bf(float f) {
  return (ushort)((__float_as_uint(f) + 0x8000u) >> 16);  // round-half-up
}

__device__ __forceinline__ uint pack_bf16(float a, float b) {
#if __has_builtin(__builtin_amdgcn_cvt_pk_bf16_f32)
  bf16x2 p = __builtin_amdgcn_cvt_pk_bf16_f32(a, b);
  return __builtin_bit_cast(uint, p);
#elif __has_builtin(__builtin_amdgcn_perm)
  uint au = __float_as_uint(a) + 0x8000u;
  uint bu = __float_as_uint(b) + 0x8000u;
  return __builtin_amdgcn_perm(bu, au, 0x07060302u);
#else
  return (uint)f2bf(a) | ((uint)f2bf(b) << 16);
#endif
}

// async global->LDS, 16B per lane; LDS dst is wave-uniform base (HW adds lane*16)
__device__ __forceinline__ void async_cp16(const void* g, void* l) {
  __builtin_amdgcn_global_load_lds(
      (const __attribute__((address_space(1))) void*)g,
      (__attribute__((address_space(3))) void*)l, 16, 0, 0);
}

// ---------------- fused prep: 4 weight casts + 3 input casts + mask bias ----------------
// blocks [0,4096): weights (1024 blocks each); [4096,28672): q/k/v (8192 each); [28672,28704): bias

__global__ __launch_bounds__(256) void prep_kernel(
    const float* __restrict__ q, const float* __restrict__ k, const float* __restrict__ v,
    const float* __restrict__ Wq, const float* __restrict__ Wk, const float* __restrict__ Wv,
    const float* __restrict__ Wo, const int* __restrict__ mask,
    ushort* qb, ushort* kb, ushort* vb,
    ushort* wqb, ushort* wkb, ushort* wvb, ushort* wob,
    float* bias) {
  int b = blockIdx.x;
  int tid = threadIdx.x;
  if (b < 4096) {
    int j = b >> 10;
    const float* in = j == 0 ? Wq : (j == 1 ? Wk : (j == 2 ? Wv : Wo));
    ushort* out = j == 0 ? wqb : (j == 1 ? wkb : (j == 2 ? wvb : wob));
    int i = (b & 1023) * 256 + tid;
    float4 f = ((const float4*)in)[i];
    uint2 o;
    o.x = pack_bf16(f.x, f.y);
    o.y = pack_bf16(f.z, f.w);
    ((uint2*)out)[i] = o;
  } else if (b < 28672) {
    int bb = b - 4096;
    int j = bb >> 13;
    const float* in = j == 0 ? q : (j == 1 ? k : v);
    ushort* out = j == 0 ? qb : (j == 1 ? kb : vb);
    int i = (bb & 8191) * 256 + tid;
    float4 f = ((const float4*)in)[i];
    uint2 o;
    o.x = pack_bf16(f.x, f.y);
    o.y = pack_bf16(f.z, f.w);
    ((uint2*)out)[i] = o;
  } else {
    int i = (b - 28672) * 256 + tid;
    bias[i] = mask[i] ? 0.0f : -1e9f;
  }
}

// ---------------- GEMM: C[m,n] = sum_k A[m,k]*W[n,k], N=K=1024, BK=64 ----------------
// mode 0: bf16 out row-major; mode 1: fp32 out row-major;
// mode 2: bf16 out per-head transposed: out[((b*16+h)*64+d)*2048 + s]
// mode 3: bf16 out row-major scaled by 0.125*log2(e)  (Q projection)
// BK=64: 32 MFMA per barrier-pair (vs 16 at BK=32) -> half the vmcnt(0) barrier drains.

__device__ __forceinline__ void gemm_body(const ushort* __restrict__ A,
                                          const ushort* __restrict__ W,
                                          void* __restrict__ Cout, int mode,
                                          int bm, int bn) {
  constexpr int N = 1024, K = 1024;
  __shared__ ushort As[128 * 64];  // 16 KB; elem(row,k) at ((k>>3)*128+row)*8+(k&7)
  __shared__ ushort Bs[128 * 64];
  const int tid = threadIdx.x;
  const int w = tid >> 6, lane = tid & 63;
  const int g = lane >> 4, cc = lane & 15;
  const int wm = (w >> 1) * 64, wn = (w & 1) * 64;

  f32x4 acc[4][4];
#pragma unroll
  for (int i = 0; i < 4; ++i)
#pragma unroll
    for (int j = 0; j < 4; ++j) acc[i][j] = (f32x4)0.0f;

  // stage one 128x64 tile of A and W: 1024 chunks each, 4 async calls/wave/matrix
  auto stage = [&](int k0) {
#pragma unroll
    for (int j = 0; j < 4; ++j) {
      int cbase = w * 256 + j * 64;
      int cid = cbase + lane;
      int row = cid & 127, kb = cid >> 7;  // kb in [0,8)
      async_cp16(A + (size_t)(bm + row) * K + k0 + kb * 8, &As[cbase * 8]);
      async_cp16(W + (size_t)(bn + row) * K + k0 + kb * 8, &Bs[cbase * 8]);
    }
  };

  stage(0);
  for (int it = 0; it < K / 64; ++it) {
    __syncthreads();  // staging drained
#pragma unroll
    for (int ks = 0; ks < 2; ++ks) {
      bf16x8 af[4], bfr[4];
#pragma unroll
      for (int mi = 0; mi < 4; ++mi)
        af[mi] = *(const bf16x8*)&As[((ks * 4 + g) * 128 + wm + mi * 16 + cc) * 8];
#pragma unroll
      for (int ni = 0; ni < 4; ++ni)
        bfr[ni] = *(const bf16x8*)&Bs[((ks * 4 + g) * 128 + wn + ni * 16 + cc) * 8];
#pragma unroll
      for (int mi = 0; mi < 4; ++mi)
#pragma unroll
        for (int ni = 0; ni < 4; ++ni)
          acc[mi][ni] =
              __builtin_amdgcn_mfma_f32_16x16x32_bf16(af[mi], bfr[ni], acc[mi][ni], 0, 0, 0);
    }
    if (it < K / 64 - 1) {
      __syncthreads();  // all LDS reads done before restage
      stage((it + 1) * 64);
    }
  }

  const float qsc = 0.18033688011112042f;
#pragma unroll
  for (int mi = 0; mi < 4; ++mi) {
#pragma unroll
    for (int ni = 0; ni < 4; ++ni) {
#pragma unroll
      for (int r = 0; r < 4; ++r) {
        int row = bm + wm + mi * 16 + g * 4 + r;
        int col = bn + wn + ni * 16 + cc;
        float val = acc[mi][ni][r];
        if (mode == 0) {
          ((ushort*)Cout)[(size_t)row * N + col] = f2bf(val);
        } else if (mode == 1) {
          ((float*)Cout)[(size_t)row * N + col] = val;
        } else if (mode == 3) {
          ((ushort*)Cout)[(size_t)row * N + col] = f2bf(val * qsc);
        } else {
          int b = row >> 11, s = row & 2047;
          int h = col >> 6, d = col & 63;
          ((ushort*)Cout)[(size_t)((b * 16 + h) * 64 + d) * 2048 + s] = f2bf(val);
        }
      }
    }
  }
}

__global__ __launch_bounds__(256) void qkv_gemm_kernel(const ushort* qb, const ushort* kb,
                                                       const ushort* vb, const ushort* wq,
                                                       const ushort* wk, const ushort* wv,
                                                       ushort* Qp, ushort* Kp, ushort* Vt) {
  int z = blockIdx.z;
  const ushort* A = z == 0 ? qb : (z == 1 ? kb : vb);
  const ushort* W = z == 0 ? wq : (z == 1 ? wk : wv);
  void* C = z == 0 ? (void*)Qp : (z == 1 ? (void*)Kp : (void*)Vt);
  gemm_body(A, W, C, z == 2 ? 2 : (z == 0 ? 3 : 0), blockIdx.y * 128, blockIdx.x * 128);
}

__global__ __launch_bounds__(256) void gemm_wo_kernel(const ushort* A, const ushort* W,
                                                      float* C) {
  gemm_body(A, W, C, 1, blockIdx.y * 128, blockIdx.x * 128);
}

// ---------------- flash attention (S^T form, exp2 domain) ----------------
// Qp: [B*S,1024] bf16 PRE-SCALED by 0.125*log2e. Kp: [B*S,1024] bf16.
// Vt: [B*H,64,2048] bf16. bias: [B,2048] fp32 (0 or -1e9). mh: [B*S,1024] bf16.
__global__ __launch_bounds__(256, 4) void attn_kernel(const ushort* __restrict__ Qp,
                                                      const ushort* __restrict__ Kp,
                                                      const ushort* __restrict__ Vt,
                                                      const float* __restrict__ bias,
                                                      ushort* __restrict__ mh) {
  constexpr int S = 2048, DM = 1024, DK = 64;
  __shared__ ushort k_lds[64 * 64];
  __shared__ ushort v_lds[64 * 64];
  __shared__ ushort pt_lds[4 * 2176];

  const int bh = blockIdx.x;
  const int qt = blockIdx.y;
  const int b = bh >> 4, h = bh & 15;
  const int tid = threadIdx.x;
  const int w = tid >> 6, lane = tid & 63;
  const int g = lane >> 4, cc = lane & 15;
  ushort* ptw = &pt_lds[w * 2176];

  const int q0 = qt * 128 + w * 32;
  bf16x8 qf[2][2];
#pragma unroll
  for (int ni = 0; ni < 2; ++ni) {
    size_t row = (size_t)(b * S + q0 + ni * 16 + cc);
#pragma unroll
    for (int ks = 0; ks < 2; ++ks)
      qf[ks][ni] = *(const bf16x8*)&Qp[row * DM + h * DK + ks * 32 + g * 8];
  }

  bf16x8 ones;
#pragma unroll
  for (int i = 0; i < 8; ++i) ones[i] = (__bf16)1.0f;

  f32x4 o_acc[4][2];
#pragma unroll
  for (int i = 0; i < 4; ++i)
#pragma unroll
    for (int j = 0; j < 2; ++j) o_acc[i][j] = (f32x4)0.0f;
  f32x4 l_acc[2] = {(f32x4)0.0f, (f32x4)0.0f};
  float m_i[2] = {-3e38f, -3e38f};
  const float* biasb = bias + b * S;

  for (int kt = 0; kt < S / 64; ++kt) {
    if (kt) __syncthreads();
#pragma unroll
    for (int j = 0; j < 2; ++j) {
      int cb = j * 256 + w * 64;
      int cid = cb + lane;
      async_cp16(Kp + (size_t)(b * S + kt * 64 + (cid & 63)) * DM + h * DK + (cid >> 6) * 8,
                 &k_lds[cb * 8]);
      async_cp16(Vt + (size_t)(bh * DK + (cid & 63)) * S + kt * 64 + (cid >> 6) * 8,
                 &v_lds[cb * 8]);
    }
    __syncthreads();

    f32x4 sacc[4][2];
#pragma unroll
    for (int mi = 0; mi < 4; ++mi)
#pragma unroll
      for (int ni = 0; ni < 2; ++ni) sacc[mi][ni] = (f32x4)0.0f;
#pragma unroll
    for (int ks = 0; ks < 2; ++ks)
#pragma unroll
      for (int mi = 0; mi < 4; ++mi) {
        bf16x8 kf = *(const bf16x8*)&k_lds[((ks * 4 + g) * 64 + mi * 16 + cc) * 8];
        sacc[mi][0] = __builtin_amdgcn_mfma_f32_16x16x32_bf16(kf, qf[ks][0], sacc[mi][0], 0, 0, 0);
        sacc[mi][1] = __builtin_amdgcn_mfma_f32_16x16x32_bf16(kf, qf[ks][1], sacc[mi][1], 0, 0, 0);
      }

    float mx[2] = {-3e38f, -3e38f};
#pragma unroll
    for (int mi = 0; mi < 4; ++mi) {
      float4 bv = *(const float4*)&biasb[kt * 64 + mi * 16 + g * 4];
      const float* bvp = &bv.x;
#pragma unroll
      for (int r = 0; r < 4; ++r) {
#pragma unroll
        for (int ni = 0; ni < 2; ++ni) {
          float t = sacc[mi][ni][r] + bvp[r];
          sacc[mi][ni][r] = t;
          mx[ni] = fmaxf(mx[ni], t);
        }
      }
    }
    float mn[2];
#pragma unroll
    for (int ni = 0; ni < 2; ++ni) {
      float m = mx[ni];
      m = fmaxf(m, __shfl_xor(m, 16, 64));
      m = fmaxf(m, __shfl_xor(m, 32, 64));
      mn[ni] = fmaxf(m_i[ni], m);
      float al = EXP2F(m_i[ni] - mn[ni]);
      m_i[ni] = mn[ni];
      l_acc[ni][0] *= al;
#pragma unroll
      for (int md = 0; md < 4; ++md)
#pragma unroll
        for (int r = 0; r < 4; ++r) o_acc[md][ni][r] *= al;
    }

#pragma unroll
    for (int mi = 0; mi < 4; ++mi)
#pragma unroll
      for (int ni = 0; ni < 2; ++ni) {
        float p0 = EXP2F(sacc[mi][ni][0] - mn[ni]);
        float p1 = EXP2F(sacc[mi][ni][1] - mn[ni]);
        float p2 = EXP2F(sacc[mi][ni][2] - mn[ni]);
        float p3 = EXP2F(sacc[mi][ni][3] - mn[ni]);
        uint2 pv;
        pv.x = pack_bf16(p0, p1);
        pv.y = pack_bf16(p2, p3);
        int base = ((mi * 2 + (g >> 1)) * 32 + ni * 16 + cc) * 8 + (g & 1) * 4;
        *(uint2*)&ptw[base] = pv;
      }

#pragma unroll
    for (int ks = 0; ks < 2; ++ks) {
      bf16x8 ptf[2];
#pragma unroll
      for (int ni = 0; ni < 2; ++ni)
        ptf[ni] = *(const bf16x8*)&ptw[((ks * 4 + g) * 32 + ni * 16 + cc) * 8];
      l_acc[0] = __builtin_amdgcn_mfma_f32_16x16x32_bf16(ones, ptf[0], l_acc[0], 0, 0, 0);
      l_acc[1] = __builtin_amdgcn_mfma_f32_16x16x32_bf16(ones, ptf[1], l_acc[1], 0, 0, 0);
#pragma unroll
      for (int md = 0; md < 4; ++md) {
        bf16x8 vf = *(const bf16x8*)&v_lds[((ks * 4 + g) * 64 + md * 16 + cc) * 8];
        o_acc[md][0] = __builtin_amdgcn_mfma_f32_16x16x32_bf16(vf, ptf[0], o_acc[md][0], 0, 0, 0);
        o_acc[md][1] = __builtin_amdgcn_mfma_f32_16x16x32_bf16(vf, ptf[1], o_acc[md][1], 0, 0, 0);
      }
    }
  }

  float rl[2];
#pragma unroll
  for (int ni = 0; ni < 2; ++ni) rl[ni] = 1.0f / l_acc[ni][0];

#pragma unroll
  for (int md = 0; md < 4; ++md)
#pragma unroll
    for (int ni = 0; ni < 2; ++ni) {
      int ql = ni * 16 + cc;
      int dbase = md * 16 + g * 4;
      *(uint*)&ptw[ql * 68 + dbase] =
          pack_bf16(o_acc[md][ni][0] * rl[ni], o_acc[md][ni][1] * rl[ni]);
      *(uint*)&ptw[ql * 68 + dbase + 2] =
          pack_bf16(o_acc[md][ni][2] * rl[ni], o_acc[md][ni][3] * rl[ni]);
    }
#pragma unroll
  for (int pass = 0; pass < 4; ++pass) {
    int ql = pass * 8 + (lane >> 3);
    int dc = lane & 7;
    uint4 val = *(const uint4*)&ptw[ql * 68 + dc * 8];
    *(uint4*)&mh[(size_t)(b * S + q0 + ql) * DM + h * DK + dc * 8] = val;
  }
}

// ---------------- launch ----------------
// ws (<=73 MB, proven): 0-16 Qp | 16-32 Kp | 32-48 Vt | 48-56 weights | 56 bias | 57-73 vb->mh
// d_out (32 MB fp32) doubles as qb/kb bf16 scratch until the final GEMM overwrites it.

extern "C" void kernel_launch(void* const* d_in, const int* in_sizes, int n_in,
                              void* d_out, int out_size, void* d_ws, size_t ws_size,
                              hipStream_t stream) {
  const float* q = (const float*)d_in[0];
  const float* k = (const float*)d_in[1];
  const float* v = (const float*)d_in[2];
  const int* mask = (const int*)d_in[3];
  const float* Wq = (const float*)d_in[4];
  const float* Wk = (const float*)d_in[5];
  const float* Wv = (const float*)d_in[6];
  const float* Wo = (const float*)d_in[7];

  const size_t MB = 1 << 20;

  char* ws = (char*)d_ws;
  ushort* Qp = (ushort*)(ws);
  ushort* Kp = (ushort*)(ws + 16 * MB);
  ushort* Vt = (ushort*)(ws + 32 * MB);
  ushort* wqb = (ushort*)(ws + 48 * MB);
  ushort* wkb = wqb + (1 << 20);
  ushort* wvb = wkb + (1 << 20);
  ushort* wob = wvb + (1 << 20);
  float* biasbuf = (float*)(ws + 56 * MB);
  ushort* vb = (ushort*)(ws + 57 * MB);
  ushort* mh = vb;  // vb dead after projections
  ushort* qb = (ushort*)d_out;
  ushort* kb = qb + (size_t)8 * 1024 * 1024;

  dim3 blk(256);

  prep_kernel<<<dim3(28704), blk, 0, stream>>>(q, k, v, Wq, Wk, Wv, Wo, mask,
                                               qb, kb, vb, wqb, wkb, wvb, wob, biasbuf);
  qkv_gemm_kernel<<<dim3(8, 64, 3), blk, 0, stream>>>(qb, kb, vb, wqb, wkb, wvb, Qp, Kp, Vt);
  attn_kernel<<<dim3(64, 16), blk, 0, stream>>>(Qp, Kp, Vt, biasbuf, mh);
  gemm_wo_kernel<<<dim3(8, 64), blk, 0, stream>>>(mh, wob, (float*)d_out);
}